// Round 9
// baseline (585.921 us; speedup 1.0000x reference)
//
#include <hip/hip_runtime.h>

typedef unsigned short u16;
typedef unsigned int u32;
typedef unsigned long long u64;
typedef __attribute__((ext_vector_type(4)))  int  i32x4;
typedef __attribute__((ext_vector_type(16))) char i8x16;

#define NPTS 131072
#define DIM  256
#define KC   2048

// 3-level fixed point: v = S1*q1 + S2*q2 + S3*q3 + eps, |eps| <= S3/2 ~ 4.8e-7
// Ratio 254 => rint(r*INV) in [-127,127]: no clamp cascade (q2/q3 clamps are
// mathematically redundant when q1 is in range: |r1| <= S1/2 -> |q2| <= 127).
// Identity S1*S3 == S2*S2 lets q2q2, q1q3, q3q1 share one accumulator weight.
constexpr float S1  = 0.0625f;                 // 127*S1 = 7.94 > max|N(0,1)|
constexpr float S2  = S1 / 254.0f;
constexpr float S3  = S2 * S2 / S1;            // = S2/254
constexpr float IS1 = 16.0f;
constexpr float IS2 = 4064.0f;                 // 254/S1
constexpr float IS3 = 1.0f / S3;
constexpr float W_A = S1 * S1;
// epilogue compares 254-scaled: v = csq254 - (254*A + B) - C/254
constexpr float R2  = 1.0f / 254.0f;

__device__ inline void quant3(float v, char& q1, char& q2, char& q3) {
    float a = fminf(fmaxf(rintf(v * IS1), -127.f), 127.f);
    float r1 = fmaf(-a, S1, v);                // exact (pow2 scale)
    float b = rintf(r1 * IS2);                 // |r1|<=S1/2 -> |b|<=127, no clamp
    float r2 = fmaf(-b, S2, r1);               // ~1-ulp error, absorbed by q3
    float c = rintf(r2 * IS3);                 // |r2|<=S2/2 -> |c|<=127
    q1 = (char)a; q2 = (char)b; q3 = (char)c;
}

// quantize one 16-dim fragment: dims kc*64 + kq*16 .. +15 of row xr
__device__ inline void quant_frag(const float4* __restrict__ xr, int kc, int kq,
                                  i8x16& o1, i8x16& o2, i8x16& o3) {
    float tmp[16];
#pragma unroll
    for (int j4 = 0; j4 < 4; ++j4) {
        float4 f = xr[kc * 16 + kq * 4 + j4];
        tmp[j4 * 4 + 0] = f.x; tmp[j4 * 4 + 1] = f.y;
        tmp[j4 * 4 + 2] = f.z; tmp[j4 * 4 + 3] = f.w;
    }
    i8x16 v1, v2, v3;
#pragma unroll
    for (int j = 0; j < 16; ++j) {
        char a, b, c;
        quant3(tmp[j], a, b, c);
        v1[j] = a; v2[j] = b; v3[j] = c;
    }
    o1 = v1; o2 = v2; o3 = v3;
}

// global -> LDS direct DMA, 16B per lane (wave-uniform base + lane*16)
#define GLD16(gsrc, ldst) \
    __builtin_amdgcn_global_load_lds( \
        (const __attribute__((address_space(1))) void*)(gsrc), \
        (__attribute__((address_space(3))) void*)(ldst), 16, 0, 0)

// ---------------------------------------------------------------------------
// Centroid prep for 16x16x64 i8 MFMA A-fragments + int 254-scaled 0.5||c||^2.
// (UNCHANGED from round 8 — verified passing.)
// Plane layout (per level): for centroid n (g16=n>>4, c=n&15), dim d
// (kc=d>>6, kq=(d>>4)&3, j=d&15): byte = ((g16*4+kc)*64 + kq*16 + c)*16 + j.
// Level l at plane offset l*KC*DIM. Also zeroes hist (blocks 0..7) and sums.
// ---------------------------------------------------------------------------
__global__ void cprep_kernel(const float* __restrict__ cen,
                             char* __restrict__ c_q,
                             int* __restrict__ c_sqi,
                             int* __restrict__ hist,
                             float* __restrict__ sums) {
    if (blockIdx.x < 8) hist[blockIdx.x * 256 + threadIdx.x] = 0;
    ((float4*)sums)[blockIdx.x * 256 + threadIdx.x] = (float4){0.f, 0.f, 0.f, 0.f};
    const int lane = threadIdx.x & 63;
    const int wv   = threadIdx.x >> 6;
    const int n    = blockIdx.x * 4 + wv;               // centroid row
    float4 v = ((const float4*)(cen + (size_t)n * DIM))[lane];  // dims lane*4..+3
    float ss = v.x * v.x + v.y * v.y + v.z * v.z + v.w * v.w;
    float fv[4] = {v.x, v.y, v.z, v.w};
    char q1[4], q2[4], q3[4];
#pragma unroll
    for (int j = 0; j < 4; ++j) quant3(fv[j], q1[j], q2[j], q3[j]);
    const int g16 = n >> 4, c = n & 15;
    const int kc  = lane >> 4;
    const int kq  = (lane >> 2) & 3;
    const size_t base = ((size_t)((g16 * 4 + kc) * 64 + kq * 16 + c)) * 16
                        + (lane & 3) * 4;
    u32 p1 = (u32)(unsigned char)q1[0] | ((u32)(unsigned char)q1[1] << 8) |
             ((u32)(unsigned char)q1[2] << 16) | ((u32)(unsigned char)q1[3] << 24);
    u32 p2 = (u32)(unsigned char)q2[0] | ((u32)(unsigned char)q2[1] << 8) |
             ((u32)(unsigned char)q2[2] << 16) | ((u32)(unsigned char)q2[3] << 24);
    u32 p3 = (u32)(unsigned char)q3[0] | ((u32)(unsigned char)q3[1] << 8) |
             ((u32)(unsigned char)q3[2] << 16) | ((u32)(unsigned char)q3[3] << 24);
    *(u32*)(c_q + base) = p1;
    *(u32*)(c_q + (size_t)KC * DIM + base) = p2;
    *(u32*)(c_q + (size_t)2 * KC * DIM + base) = p3;
#pragma unroll
    for (int off = 32; off > 0; off >>= 1) ss += __shfl_xor(ss, off);
    if (lane == 0) c_sqi[n] = (int)rintf(ss * (0.5f * 254.0f / W_A));
}

// ---------------------------------------------------------------------------
// Assignment via mfma_i32_16x16x64_i8, 32 POINTS per wave (two 16-col B-tiles
// sharing every A-fragment read): per kc, 6 ds_read_b128 feed 24 MFMAs
// (4 quadrants x 6 products) vs round-8's 12 -> LDS-read demand per CU halves
// (3072->1536 cy/tile) while MFMA demand (3917 cy/tile) is unchanged, and
// barrier/epilogue overhead amortizes over 2x MFMA work.
// Registers: xq 2x48 + acc 12x4 + temps ~ 195 -> launch_bounds(256,2) caps at
// 256 (no spill; R4's spill was demand ~300 @ cap 128). 8 waves/CU = 2 blocks
// (LDS 80KB x 2 = 160KB exactly); the paired block covers stall phases.
// Staging: 3-deep ring of full tiles (24KB), counted vmcnt(6) (6 GLD16 per
// stage at 256 thr; never 0 mid-loop); stage(t+2) is issued after the barrier
// into the buffer fully read at tile t-1 (sealed by that barrier).
// Per quadrant (cen-group g x point-group p): accA += q1c*q1x;
// accB += q1c*q2x + q2c*q1x; accC += q2c*q2x + q1c*q3x + q3c*q1x.
// Epilogue: v = csq254 - (254*A + B) - C/254   (mul24 exact, |A| < 2^23)
// D layout: col = lane&15 (point), row = (lane>>4)*4 + reg (m89/m121).
// ---------------------------------------------------------------------------
__global__ __launch_bounds__(256, 2) void assign_kernel(
    const float* __restrict__ x, const char* __restrict__ c_q,
    const int* __restrict__ c_sqi, int* __restrict__ assigns,
    int* __restrict__ hist) {
    __shared__ char lds_c[3 * 24576 + 8192];   // 3 stage bufs + csq = 80KB

    const int tid  = threadIdx.x;       // 0..255
    const int lane = tid & 63;
    const int wv   = tid >> 6;          // 0..3
    const int p16  = lane & 15;         // point-column within B-tile
    const int kq   = lane >> 4;         // K-quarter / D-row group

    const char* cl1 = c_q;
    const char* cl2 = c_q + (size_t)KC * DIM;
    const char* cl3 = c_q + (size_t)2 * KC * DIM;

    // ---- prologue DMA: csq (2 calls) then stage0 (6) then stage1 (6) ----
    GLD16((const char*)c_sqi + tid * 16,         lds_c + 73728 + tid * 16);
    GLD16((const char*)c_sqi + (tid + 256) * 16, lds_c + 73728 + (tid + 256) * 16);
#pragma unroll
    for (int st = 0; st < 2; ++st) {
        char* d = lds_c + st * 24576;
        const size_t so = (size_t)st * 8192;
        GLD16(cl1 + so + tid * 16,        d + tid * 16);
        GLD16(cl1 + so + 4096 + tid * 16, d + 4096 + tid * 16);
        GLD16(cl2 + so + tid * 16,        d + 8192 + tid * 16);
        GLD16(cl2 + so + 4096 + tid * 16, d + 8192 + 4096 + tid * 16);
        GLD16(cl3 + so + tid * 16,        d + 16384 + tid * 16);
        GLD16(cl3 + so + 4096 + tid * 16, d + 16384 + 4096 + tid * 16);
    }

    // ---- quantize this lane's TWO points (B-tiles a, b) ----
    const int mA = blockIdx.x * 128 + wv * 32 + p16;   // tile a point
    const int mB = mA + 16;                            // tile b point
    const float4* xrA = (const float4*)(x + (size_t)mA * DIM);
    const float4* xrB = (const float4*)(x + (size_t)mB * DIM);
    i8x16 xa1[4], xa2[4], xa3[4], xb1[4], xb2[4], xb3[4];
#pragma unroll
    for (int kc = 0; kc < 4; ++kc) {
        quant_frag(xrA, kc, kq, xa1[kc], xa2[kc], xa3[kc]);
        quant_frag(xrB, kc, kq, xb1[kc], xb2[kc], xb3[kc]);
    }

    float bestA = 3.4e38f, bestB = 3.4e38f;
    int bixA = 0, bixB = 0;
    int b3 = 0;        // current stage buffer (cycles 0,1,2)
    const int* csqL = (const int*)(lds_c + 73728);

    for (int t = 0; t < 64; ++t) {
        // steady state: {stage(t), stage(t+1)} outstanding (12 loads); wait
        // own stage(t) (leave 6). t=0 also drains csq. Last tile: drain all.
        if (t == 63) {
            asm volatile("s_waitcnt vmcnt(0)" ::: "memory");
        } else {
            asm volatile("s_waitcnt vmcnt(6)" ::: "memory");
        }
        __builtin_amdgcn_s_barrier();
        __builtin_amdgcn_sched_barrier(0);
        // issue stage(t+2) into buf (b3+2)%3: fully read at tile t-1 and
        // sealed by the barrier just crossed (all waves past it).
        if (t + 2 < 64) {
            int pn = b3 + 2; if (pn >= 3) pn -= 3;
            char* d = lds_c + pn * 24576;
            const size_t so = (size_t)(t + 2) * 8192;
            GLD16(cl1 + so + tid * 16,        d + tid * 16);
            GLD16(cl1 + so + 4096 + tid * 16, d + 4096 + tid * 16);
            GLD16(cl2 + so + tid * 16,        d + 8192 + tid * 16);
            GLD16(cl2 + so + 4096 + tid * 16, d + 8192 + 4096 + tid * 16);
            GLD16(cl3 + so + tid * 16,        d + 16384 + tid * 16);
            GLD16(cl3 + so + 4096 + tid * 16, d + 16384 + 4096 + tid * 16);
        }
        const char* cb = lds_c + b3 * 24576;
        // 12 named accumulators: acc{A,B,C}{cen-group}{point-group}
        i32x4 accA0a = {}, accB0a = {}, accC0a = {};
        i32x4 accA1a = {}, accB1a = {}, accC1a = {};
        i32x4 accA0b = {}, accB0b = {}, accC0b = {};
        i32x4 accA1b = {}, accB1b = {}, accC1b = {};
        __builtin_amdgcn_s_setprio(1);
#pragma unroll
        for (int kc = 0; kc < 4; ++kc) {
            const int off = kc * 1024 + lane * 16;
            i32x4 c1a = __builtin_bit_cast(i32x4, *(const i8x16*)(cb + off));
            i32x4 c2a = __builtin_bit_cast(i32x4, *(const i8x16*)(cb + 8192 + off));
            i32x4 c3a = __builtin_bit_cast(i32x4, *(const i8x16*)(cb + 16384 + off));
            i32x4 c1b = __builtin_bit_cast(i32x4, *(const i8x16*)(cb + 4096 + off));
            i32x4 c2b = __builtin_bit_cast(i32x4, *(const i8x16*)(cb + 12288 + off));
            i32x4 c3b = __builtin_bit_cast(i32x4, *(const i8x16*)(cb + 20480 + off));
            i32x4 a1 = __builtin_bit_cast(i32x4, xa1[kc]);
            i32x4 a2 = __builtin_bit_cast(i32x4, xa2[kc]);
            i32x4 a3 = __builtin_bit_cast(i32x4, xa3[kc]);
            i32x4 b1 = __builtin_bit_cast(i32x4, xb1[kc]);
            i32x4 b2 = __builtin_bit_cast(i32x4, xb2[kc]);
            i32x4 b3v = __builtin_bit_cast(i32x4, xb3[kc]);
            // 12 independent chains; same-acc MFMAs separated by >=3 ops
            accA0a = __builtin_amdgcn_mfma_i32_16x16x64_i8(c1a, a1, accA0a, 0, 0, 0);
            accA0b = __builtin_amdgcn_mfma_i32_16x16x64_i8(c1a, b1, accA0b, 0, 0, 0);
            accA1a = __builtin_amdgcn_mfma_i32_16x16x64_i8(c1b, a1, accA1a, 0, 0, 0);
            accA1b = __builtin_amdgcn_mfma_i32_16x16x64_i8(c1b, b1, accA1b, 0, 0, 0);
            accB0a = __builtin_amdgcn_mfma_i32_16x16x64_i8(c1a, a2, accB0a, 0, 0, 0);
            accB0b = __builtin_amdgcn_mfma_i32_16x16x64_i8(c1a, b2, accB0b, 0, 0, 0);
            accB1a = __builtin_amdgcn_mfma_i32_16x16x64_i8(c1b, a2, accB1a, 0, 0, 0);
            accB1b = __builtin_amdgcn_mfma_i32_16x16x64_i8(c1b, b2, accB1b, 0, 0, 0);
            accC0a = __builtin_amdgcn_mfma_i32_16x16x64_i8(c2a, a2, accC0a, 0, 0, 0);
            accC0b = __builtin_amdgcn_mfma_i32_16x16x64_i8(c2a, b2, accC0b, 0, 0, 0);
            accC1a = __builtin_amdgcn_mfma_i32_16x16x64_i8(c2b, a2, accC1a, 0, 0, 0);
            accC1b = __builtin_amdgcn_mfma_i32_16x16x64_i8(c2b, b2, accC1b, 0, 0, 0);
            accB0a = __builtin_amdgcn_mfma_i32_16x16x64_i8(c2a, a1, accB0a, 0, 0, 0);
            accB0b = __builtin_amdgcn_mfma_i32_16x16x64_i8(c2a, b1, accB0b, 0, 0, 0);
            accB1a = __builtin_amdgcn_mfma_i32_16x16x64_i8(c2b, a1, accB1a, 0, 0, 0);
            accB1b = __builtin_amdgcn_mfma_i32_16x16x64_i8(c2b, b1, accB1b, 0, 0, 0);
            accC0a = __builtin_amdgcn_mfma_i32_16x16x64_i8(c1a, a3, accC0a, 0, 0, 0);
            accC0b = __builtin_amdgcn_mfma_i32_16x16x64_i8(c1a, b3v, accC0b, 0, 0, 0);
            accC1a = __builtin_amdgcn_mfma_i32_16x16x64_i8(c1b, a3, accC1a, 0, 0, 0);
            accC1b = __builtin_amdgcn_mfma_i32_16x16x64_i8(c1b, b3v, accC1b, 0, 0, 0);
            accC0a = __builtin_amdgcn_mfma_i32_16x16x64_i8(c3a, a1, accC0a, 0, 0, 0);
            accC0b = __builtin_amdgcn_mfma_i32_16x16x64_i8(c3a, b1, accC0b, 0, 0, 0);
            accC1a = __builtin_amdgcn_mfma_i32_16x16x64_i8(c3b, a1, accC1a, 0, 0, 0);
            accC1b = __builtin_amdgcn_mfma_i32_16x16x64_i8(c3b, b1, accC1b, 0, 0, 0);
        }
        __builtin_amdgcn_s_setprio(0);
        b3 += 1; if (b3 == 3) b3 = 0;

        // epilogue: v = csq254 - (254*A + B) - C/254 (254x score, same argmin)
        // cen rows: group0 -> n = t*32 + kq*4 + r; group1 -> +16 (both tiles)
        {
            int4 cs0 = *(const int4*)(csqL + t * 32 + kq * 4);
            int4 cs1 = *(const int4*)(csqL + t * 32 + 16 + kq * 4);
            const int n0 = t * 32 + kq * 4;
            int csa0[4] = {cs0.x, cs0.y, cs0.z, cs0.w};
            int csa1[4] = {cs1.x, cs1.y, cs1.z, cs1.w};
#pragma unroll
            for (int r = 0; r < 4; ++r) {
                int D0a = __mul24(accA0a[r], 254) + accB0a[r];
                float v0a = fmaf((float)accC0a[r], -R2, (float)(csa0[r] - D0a));
                if (v0a < bestA) { bestA = v0a; bixA = n0 + r; }
                int D0b = __mul24(accA0b[r], 254) + accB0b[r];
                float v0b = fmaf((float)accC0b[r], -R2, (float)(csa0[r] - D0b));
                if (v0b < bestB) { bestB = v0b; bixB = n0 + r; }
            }
#pragma unroll
            for (int r = 0; r < 4; ++r) {
                int D1a = __mul24(accA1a[r], 254) + accB1a[r];
                float v1a = fmaf((float)accC1a[r], -R2, (float)(csa1[r] - D1a));
                if (v1a < bestA) { bestA = v1a; bixA = n0 + 16 + r; }
                int D1b = __mul24(accA1b[r], 254) + accB1b[r];
                float v1b = fmaf((float)accC1b[r], -R2, (float)(csa1[r] - D1b));
                if (v1b < bestB) { bestB = v1b; bixB = n0 + 16 + r; }
            }
        }
    }

    // merge across the 4 kq lanes holding rows for the same point column
    // (symmetric butterfly: afterwards every lane holds the global min)
    {
        float ov; int oi;
        ov = __shfl_xor(bestA, 16); oi = __shfl_xor(bixA, 16);
        if (ov < bestA || (ov == bestA && oi < bixA)) { bestA = ov; bixA = oi; }
        ov = __shfl_xor(bestA, 32); oi = __shfl_xor(bixA, 32);
        if (ov < bestA || (ov == bestA && oi < bixA)) { bestA = ov; bixA = oi; }
        ov = __shfl_xor(bestB, 16); oi = __shfl_xor(bixB, 16);
        if (ov < bestB || (ov == bestB && oi < bixB)) { bestB = ov; bixB = oi; }
        ov = __shfl_xor(bestB, 32); oi = __shfl_xor(bixB, 32);
        if (ov < bestB || (ov == bestB && oi < bixB)) { bestB = ov; bixB = oi; }
    }
    if (lane < 16) {
        assigns[mA] = bixA;                // mA = blk*128 + wv*32 + lane
        atomicAdd(&hist[bixA], 1);
    } else if (lane < 32) {
        assigns[mB] = bixB;                // mB = blk*128 + wv*32 + (lane&15) + 16
        atomicAdd(&hist[bixB], 1);
    }
}

// Exclusive prefix sum over KC=2048 counts; one block of 256 threads x 8 each.
__global__ void scan_kernel(const int* __restrict__ hist,
                            int* __restrict__ base_,
                            int* __restrict__ cursor) {
    __shared__ int tmp[256];
    const int tid = threadIdx.x;
    int v[8], s = 0;
#pragma unroll
    for (int j = 0; j < 8; ++j) { v[j] = hist[tid * 8 + j]; s += v[j]; }
    tmp[tid] = s;
    __syncthreads();
    for (int off = 1; off < 256; off <<= 1) {
        int t = (tid >= off) ? tmp[tid - off] : 0;
        __syncthreads();
        tmp[tid] += t;
        __syncthreads();
    }
    int ex = tmp[tid] - s;
#pragma unroll
    for (int j = 0; j < 8; ++j) {
        base_[tid * 8 + j] = ex;
        cursor[tid * 8 + j] = ex;
        ex += v[j];
    }
}

__global__ void reorder_kernel(const int* __restrict__ assigns,
                               int* __restrict__ cursor,
                               int* __restrict__ order) {
    const int p = blockIdx.x * 256 + threadIdx.x;
    const int a = assigns[p];
    int pos = atomicAdd(&cursor[a], 1);
    order[pos] = p;
}

// ---------------------------------------------------------------------------
// Skew-immune segmented reduce: each block owns 256 consecutive rows of the
// SORTED order array; thread t owns dim t (coalesced 1KB row reads). Flush to
// sums[] with atomics only at cluster boundaries (block-uniform branches).
// ---------------------------------------------------------------------------
__global__ void reduce_kernel(const float* __restrict__ x,
                              const int* __restrict__ order,
                              const int* __restrict__ assigns,
                              float* __restrict__ sums) {
    const int tid = threadIdx.x;
    const int r0 = blockIdx.x * 256;
    float acc = 0.f;
    int cur = assigns[order[r0]];
    for (int r = 0; r < 256; r += 4) {
        int p0 = order[r0 + r + 0], p1 = order[r0 + r + 1];
        int p2 = order[r0 + r + 2], p3 = order[r0 + r + 3];
        float v0 = x[(size_t)p0 * DIM + tid];
        float v1 = x[(size_t)p1 * DIM + tid];
        float v2 = x[(size_t)p2 * DIM + tid];
        float v3 = x[(size_t)p3 * DIM + tid];
        int a0 = assigns[p0], a1 = assigns[p1], a2 = assigns[p2], a3 = assigns[p3];
        if (a0 != cur) { unsafeAtomicAdd(&sums[(size_t)cur * DIM + tid], acc); acc = 0.f; cur = a0; }
        acc += v0;
        if (a1 != cur) { unsafeAtomicAdd(&sums[(size_t)cur * DIM + tid], acc); acc = 0.f; cur = a1; }
        acc += v1;
        if (a2 != cur) { unsafeAtomicAdd(&sums[(size_t)cur * DIM + tid], acc); acc = 0.f; cur = a2; }
        acc += v2;
        if (a3 != cur) { unsafeAtomicAdd(&sums[(size_t)cur * DIM + tid], acc); acc = 0.f; cur = a3; }
        acc += v3;
    }
    unsafeAtomicAdd(&sums[(size_t)cur * DIM + tid], acc);
}

__global__ void finalize_kernel(const float* __restrict__ sums,
                                const int* __restrict__ hist,
                                const float* __restrict__ cen,
                                float* __restrict__ out) {
    const int id = blockIdx.x * 256 + threadIdx.x;   // KC*64 items
    const int k = id >> 6;
    const int cnt = hist[k];
    float4 s = ((const float4*)sums)[id];
    float4 c = ((const float4*)cen)[id];
    float4 o;
    if (cnt > 0) {
        float r = 1.0f / (float)cnt;
        o.x = s.x * r; o.y = s.y * r; o.z = s.z * r; o.w = s.w * r;
    } else {
        o = c;
    }
    ((float4*)out)[id] = o;
}

extern "C" void kernel_launch(void* const* d_in, const int* in_sizes, int n_in,
                              void* d_out, int out_size, void* d_ws, size_t ws_size,
                              hipStream_t stream) {
    (void)in_sizes; (void)n_in; (void)out_size; (void)ws_size;
    const float* x   = (const float*)d_in[0];
    const float* cen = (const float*)d_in[1];
    float* out = (float*)d_out;

    char* ws = (char*)d_ws;
    size_t off = 0;
    char* c_q = (char*)(ws + off);           off += (size_t)3 * KC * DIM;      // 1.5MB
    int* c_sqi = (int*)(ws + off);           off += (size_t)KC * 4;            // 8KB
    int* assigns = (int*)(ws + off);         off += (size_t)NPTS * 4;          // 512KB
    int* hist = (int*)(ws + off);            off += (size_t)KC * 4;            // 8KB
    int* base_ = (int*)(ws + off);           off += (size_t)KC * 4;            // 8KB
    int* cursor = (int*)(ws + off);          off += (size_t)KC * 4;            // 8KB
    int* order = (int*)(ws + off);           off += (size_t)NPTS * 4;          // 512KB
    float* sums = (float*)(ws + off);        off += (size_t)KC * DIM * 4;      // 2MB

    cprep_kernel<<<KC / 4, 256, 0, stream>>>(cen, c_q, c_sqi, hist, sums);
    assign_kernel<<<NPTS / 128, 256, 0, stream>>>(x, c_q, c_sqi, assigns, hist);
    scan_kernel<<<1, 256, 0, stream>>>(hist, base_, cursor);
    reorder_kernel<<<NPTS / 256, 256, 0, stream>>>(assigns, cursor, order);
    reduce_kernel<<<NPTS / 256, 256, 0, stream>>>(x, order, assigns, sums);
    finalize_kernel<<<KC * 64 / 256, 256, 0, stream>>>(sums, hist, cen, out);
}